// Round 1
// baseline (330.664 us; speedup 1.0000x reference)
//
#include <hip/hip_runtime.h>

#define BB 16
#define TT 4096
#define DD 512

// workspace float offsets
#define OFF_Q    64                       // 3*BB*DD floats
#define OFF_P    (OFF_Q + 3*BB*DD)        // 3*BB*TT floats
#define OFF_W    (OFF_P + 3*BB*TT)        // 3*BB*TT floats
#define OFF_POOL (OFF_W + 3*BB*TT)        // 3*BB*DD floats

// ---------------- K1: mask layout detection + per-batch lengths --------------
__global__ void __launch_bounds__(1024) k_lengths(const unsigned char* mask, int* lengths) {
    __shared__ int sflag;
    __shared__ int sred[16];
    const int tid = threadIdx.x;
    if (tid == 0) sflag = 0;
    __syncthreads();
    // bytes at offset ==1 (mod 4): always 0 for int32/float32 0/1 values,
    // nonzero inside uint8 padded runs (len>=T/2 guarantees runs exist w.h.p.)
    int f = 0;
    for (int idx = tid * 4 + 1; idx < BB * TT; idx += 1024 * 4)
        f |= (mask[idx] != 0);
    if (f) atomicOr(&sflag, 1);
    __syncthreads();
    const bool byte_layout = (sflag != 0);
    const int* m32 = (const int*)mask;
    for (int b = 0; b < BB; b++) {
        int cnt = 0;
        if (byte_layout) {
            for (int t = tid; t < TT; t += 1024) cnt += (mask[b * TT + t] != 0);
        } else {
            for (int t = tid; t < TT; t += 1024) cnt += (m32[b * TT + t] != 0);
        }
        int v = cnt;
        #pragma unroll
        for (int m = 32; m >= 1; m >>= 1) v += __shfl_xor(v, m, 64);
        if ((tid & 63) == 0) sred[tid >> 6] = v;
        __syncthreads();
        if (tid < 16) {
            int x = sred[tid];
            #pragma unroll
            for (int m = 8; m >= 1; m >>= 1) x += __shfl_xor(x, m, 16);
            if (tid == 0) lengths[b] = TT - x;   // number of unmasked positions
        }
        __syncthreads();
    }
}

// ---------------- K2: q_i[b,d] = sum_e s_prev[b,e] * Vw[i,e,d] ---------------
__global__ void __launch_bounds__(256) k_q(const float* __restrict__ s_prev,
                                           const float* __restrict__ Vw,
                                           float* __restrict__ q) {
    const int ib = blockIdx.x;            // i*BB + b, 48 blocks
    const int b = ib % BB;
    const int i = ib / BB;
    const int d0 = threadIdx.x;           // d0 and d0+256
    const float* sp = s_prev + b * DD;
    const float* W = Vw + (size_t)i * DD * DD;
    float a0 = 0.f, a1 = 0.f;
    for (int e = 0; e < DD; e++) {
        const float se = sp[e];
        a0 += se * W[e * DD + d0];
        a1 += se * W[e * DD + d0 + 256];
    }
    q[(size_t)ib * DD + d0] = a0;
    q[(size_t)ib * DD + d0 + 256] = a1;
}

// ---------------- K3: p_i[b,t] = enc_hs[b,t,:] . q_i[b,:] --------------------
__global__ void __launch_bounds__(256) k_scores(const float* __restrict__ enc,
                                                const float* __restrict__ q,
                                                float* __restrict__ p) {
    const int wid = blockIdx.x * 4 + (threadIdx.x >> 6);   // row = b*T + t
    const int lane = threadIdx.x & 63;
    const int b = wid >> 12;
    const int t = wid & (TT - 1);
    const float4* e4 = (const float4*)(enc + (size_t)wid * DD);
    const float4 x0 = e4[lane * 2];
    const float4 x1 = e4[lane * 2 + 1];
    float acc[3];
    #pragma unroll
    for (int i = 0; i < 3; i++) {
        const float4* q4 = (const float4*)(q + (size_t)(i * BB + b) * DD);
        const float4 y0 = q4[lane * 2];
        const float4 y1 = q4[lane * 2 + 1];
        acc[i] = x0.x * y0.x + x0.y * y0.y + x0.z * y0.z + x0.w * y0.w
               + x1.x * y1.x + x1.y * y1.y + x1.z * y1.z + x1.w * y1.w;
    }
    #pragma unroll
    for (int m = 32; m >= 1; m >>= 1) {
        acc[0] += __shfl_xor(acc[0], m, 64);
        acc[1] += __shfl_xor(acc[1], m, 64);
        acc[2] += __shfl_xor(acc[2], m, 64);
    }
    if (lane == 0) {
        p[(size_t)(0 * BB + b) * TT + t] = acc[0];
        p[(size_t)(1 * BB + b) * TT + t] = acc[1];
        p[(size_t)(2 * BB + b) * TT + t] = acc[2];
    }
}

// ------- K4: windowed softmax per (i,b); emit pool weights w and att ---------
__global__ void __launch_bounds__(1024) k_softmax(const float* __restrict__ p,
                                                  const int* __restrict__ lengths,
                                                  float* __restrict__ w,
                                                  float* __restrict__ att_out) {
    __shared__ float sred[16];
    __shared__ float sbc;
    const int ib = blockIdx.x;            // 48 blocks
    const int b = ib % BB;
    const int i = ib / BB;
    const int k = i + 1;
    const float invk = 1.0f / (float)k;
    int V = lengths[b] - k + 1;           // count of valid window positions
    if (V < 0) V = 0;
    const float* pp = p + (size_t)ib * TT;
    const int tid = threadIdx.x;

    // phase 1: max over valid windowed scores
    float local = -3.4e38f;
    for (int l = tid; l < V; l += 1024) {
        float s = pp[l];
        if (k > 1) s += pp[l + 1];
        if (k > 2) s += pp[l + 2];
        local = fmaxf(local, s * invk);
    }
    float v = local;
    #pragma unroll
    for (int m = 32; m >= 1; m >>= 1) v = fmaxf(v, __shfl_xor(v, m, 64));
    if ((tid & 63) == 0) sred[tid >> 6] = v;
    __syncthreads();
    if (tid < 16) {
        float x = sred[tid];
        #pragma unroll
        for (int m = 8; m >= 1; m >>= 1) x = fmaxf(x, __shfl_xor(x, m, 16));
        if (tid == 0) sbc = x;
    }
    __syncthreads();
    const float mmax = sbc;
    __syncthreads();

    // phase 2: sum of exps
    float lsum = 0.f;
    for (int l = tid; l < V; l += 1024) {
        float s = pp[l];
        if (k > 1) s += pp[l + 1];
        if (k > 2) s += pp[l + 2];
        lsum += __expf(s * invk - mmax);
    }
    v = lsum;
    #pragma unroll
    for (int m = 32; m >= 1; m >>= 1) v += __shfl_xor(v, m, 64);
    if ((tid & 63) == 0) sred[tid >> 6] = v;
    __syncthreads();
    if (tid < 16) {
        float x = sred[tid];
        #pragma unroll
        for (int m = 8; m >= 1; m >>= 1) x += __shfl_xor(x, m, 16);
        if (tid == 0) sbc = x;
    }
    __syncthreads();
    const float inv = 1.0f / sbc;

    // phase 3: pool weights w_i[b,t] = (1/k) * sum_{j<k} a_i[b,t-j]
    for (int t = tid; t < TT; t += 1024) {
        float acc = 0.f;
        #pragma unroll
        for (int j = 0; j < 3; j++) {
            if (j < k) {
                const int l = t - j;
                if (l >= 0 && l < V) {
                    float s = pp[l];
                    if (k > 1) s += pp[l + 1];
                    if (k > 2) s += pp[l + 2];
                    acc += __expf(s * invk - mmax);
                }
            }
        }
        acc *= inv * invk;
        w[(size_t)ib * TT + t] = acc;
        if (i == 0) att_out[(size_t)b * TT + t] = acc;  // k=1: w == att
    }
}

// ---------------- K5: pooled_i[b,d] = sum_t w_i[b,t] * enc_hs[b,t,d] ---------
__global__ void __launch_bounds__(128) k_pool(const float* __restrict__ enc,
                                              const float* __restrict__ w,
                                              float* __restrict__ pooled) {
    const int b = blockIdx.x;
    const int t0 = blockIdx.y * 64;
    const int d4 = threadIdx.x;           // float4 column, 0..127
    float4 a0 = {0, 0, 0, 0}, a1 = {0, 0, 0, 0}, a2 = {0, 0, 0, 0};
    const float* wb0 = w + (size_t)(0 * BB + b) * TT;
    const float* wb1 = w + (size_t)(1 * BB + b) * TT;
    const float* wb2 = w + (size_t)(2 * BB + b) * TT;
    for (int t = t0; t < t0 + 64; ++t) {
        const float4 x = ((const float4*)(enc + ((size_t)b * TT + t) * DD))[d4];
        const float w0 = wb0[t], w1 = wb1[t], w2 = wb2[t];
        a0.x += w0 * x.x; a0.y += w0 * x.y; a0.z += w0 * x.z; a0.w += w0 * x.w;
        a1.x += w1 * x.x; a1.y += w1 * x.y; a1.z += w1 * x.z; a1.w += w1 * x.w;
        a2.x += w2 * x.x; a2.y += w2 * x.y; a2.z += w2 * x.z; a2.w += w2 * x.w;
    }
    float* p0 = pooled + (size_t)(0 * BB + b) * DD + d4 * 4;
    float* p1 = pooled + (size_t)(1 * BB + b) * DD + d4 * 4;
    float* p2 = pooled + (size_t)(2 * BB + b) * DD + d4 * 4;
    atomicAdd(p0 + 0, a0.x); atomicAdd(p0 + 1, a0.y); atomicAdd(p0 + 2, a0.z); atomicAdd(p0 + 3, a0.w);
    atomicAdd(p1 + 0, a1.x); atomicAdd(p1 + 1, a1.y); atomicAdd(p1 + 2, a1.z); atomicAdd(p1 + 3, a1.w);
    atomicAdd(p2 + 0, a2.x); atomicAdd(p2 + 1, a2.y); atomicAdd(p2 + 2, a2.z); atomicAdd(p2 + 3, a2.w);
}

// -------- K6: ctx[b,e] = sum_i (pooled_i[b,:] . Ww[i,e,:]) + sum_i Wb[i,e] ---
__global__ void __launch_bounds__(256) k_ctx(const float* __restrict__ pooled,
                                             const float* __restrict__ Ww,
                                             const float* __restrict__ Wb,
                                             float* __restrict__ ctx) {
    const int wid = blockIdx.x * 4 + (threadIdx.x >> 6);   // b*512 + e
    const int lane = threadIdx.x & 63;
    const int b = wid >> 9;
    const int e = wid & 511;
    float acc = 0.f;
    #pragma unroll
    for (int i = 0; i < 3; i++) {
        const float4* pr = (const float4*)(pooled + (size_t)(i * BB + b) * DD);
        const float4* wr = (const float4*)(Ww + ((size_t)i * DD + e) * DD);
        const float4 p0 = pr[lane * 2], p1 = pr[lane * 2 + 1];
        const float4 w0 = wr[lane * 2], w1 = wr[lane * 2 + 1];
        acc += p0.x * w0.x + p0.y * w0.y + p0.z * w0.z + p0.w * w0.w
             + p1.x * w1.x + p1.y * w1.y + p1.z * w1.z + p1.w * w1.w;
    }
    #pragma unroll
    for (int m = 32; m >= 1; m >>= 1) acc += __shfl_xor(acc, m, 64);
    if (lane == 0)
        ctx[(size_t)b * DD + e] = acc + Wb[e] + Wb[DD + e] + Wb[2 * DD + e];
}

extern "C" void kernel_launch(void* const* d_in, const int* in_sizes, int n_in,
                              void* d_out, int out_size, void* d_ws, size_t ws_size,
                              hipStream_t stream) {
    const float* s_prev = (const float*)d_in[0];
    const float* enc    = (const float*)d_in[1];
    const void*  mask   = d_in[2];
    const float* Vw     = (const float*)d_in[3];
    // d_in[4] = Vb: dead — constant shift under softmax
    const float* Ww     = (const float*)d_in[5];
    const float* Wb     = (const float*)d_in[6];

    float* out = (float*)d_out;
    float* ctx = out;              // [B, D]
    float* att = out + BB * DD;    // [B, T]

    float* W       = (float*)d_ws;
    int*   lengths = (int*)d_ws;                 // 16 ints in first 64 floats
    float* q       = W + OFF_Q;
    float* p       = W + OFF_P;
    float* wbuf    = W + OFF_W;
    float* pooled  = W + OFF_POOL;

    hipMemsetAsync(pooled, 0, 3 * BB * DD * sizeof(float), stream);
    k_lengths<<<1, 1024, 0, stream>>>((const unsigned char*)mask, lengths);
    k_q<<<3 * BB, 256, 0, stream>>>(s_prev, Vw, q);
    k_scores<<<BB * TT / 4, 256, 0, stream>>>(enc, q, p);
    k_softmax<<<3 * BB, 1024, 0, stream>>>(p, lengths, wbuf, att);
    k_pool<<<dim3(BB, 64), 128, 0, stream>>>(enc, wbuf, pooled);
    k_ctx<<<BB * DD / 4, 256, 0, stream>>>(pooled, Ww, Wb, ctx);
}

// Round 2
// 278.383 us; speedup vs baseline: 1.1878x; 1.1878x over previous
//
#include <hip/hip_runtime.h>

#define BB 16
#define TT 4096
#define DD 512
#define NCHUNK 64    // t-chunks for pooling partials

// workspace float offsets
#define OFF_Q    64                        // 3*BB*DD floats
#define OFF_P    (OFF_Q + 3*BB*DD)         // 3*BB*TT floats
#define OFF_W    (OFF_P + 3*BB*TT)         // 3*BB*TT floats
#define OFF_POOL (OFF_W + 3*BB*TT)         // 3*BB*DD floats
#define OFF_PART (OFF_POOL + 3*BB*DD)      // 3*NCHUNK*BB*DD floats (6 MB)

// ---------------- K1: mask layout detection + per-batch lengths --------------
// One wave per batch row (16 waves); block-wide byte-layout detection first.
__global__ void __launch_bounds__(1024) k_lengths(const unsigned char* mask, int* lengths) {
    __shared__ int sflag;
    const int tid = threadIdx.x;
    if (tid == 0) sflag = 0;
    __syncthreads();
    // bytes at offset ==1 (mod 4): always 0 for int32/float32 0/1 values,
    // nonzero inside uint8 padded runs (len>=T/2 guarantees runs exist w.h.p.)
    int f = 0;
    for (int idx = tid * 4 + 1; idx < BB * TT; idx += 1024 * 4)
        f |= (mask[idx] != 0);
    if (f) atomicOr(&sflag, 1);
    __syncthreads();
    const bool byte_layout = (sflag != 0);
    const int* m32 = (const int*)mask;
    const int b = tid >> 6;       // wave id = batch row
    const int lane = tid & 63;
    int cnt = 0;
    if (byte_layout) {
        for (int t = lane; t < TT; t += 64) cnt += (mask[b * TT + t] != 0);
    } else {
        for (int t = lane; t < TT; t += 64) cnt += (m32[b * TT + t] != 0);
    }
    #pragma unroll
    for (int m = 32; m >= 1; m >>= 1) cnt += __shfl_xor(cnt, m, 64);
    if (lane == 0) lengths[b] = TT - cnt;   // number of unmasked positions
}

// ---------------- K2: q_i[b,d] = sum_e s_prev[b,e] * Vw[i,e,d] ---------------
__global__ void __launch_bounds__(256) k_q(const float* __restrict__ s_prev,
                                           const float* __restrict__ Vw,
                                           float* __restrict__ q) {
    const int ib = blockIdx.x;            // i*BB + b, 48 blocks
    const int b = ib % BB;
    const int i = ib / BB;
    const int d0 = threadIdx.x;           // d0 and d0+256
    const float* sp = s_prev + b * DD;
    const float* W = Vw + (size_t)i * DD * DD;
    float a0 = 0.f, a1 = 0.f;
    for (int e = 0; e < DD; e++) {
        const float se = sp[e];
        a0 += se * W[e * DD + d0];
        a1 += se * W[e * DD + d0 + 256];
    }
    q[(size_t)ib * DD + d0] = a0;
    q[(size_t)ib * DD + d0 + 256] = a1;
}

// ---------------- K3: p_i[b,t] = enc_hs[b,t,:] . q_i[b,:] --------------------
// Skips rows t >= len_b (those p values are never read downstream).
__global__ void __launch_bounds__(256) k_scores(const float* __restrict__ enc,
                                                const float* __restrict__ q,
                                                const int* __restrict__ lengths,
                                                float* __restrict__ p) {
    const int wid = blockIdx.x * 4 + (threadIdx.x >> 6);   // row = b*T + t
    const int lane = threadIdx.x & 63;
    const int b = wid >> 12;
    const int t = wid & (TT - 1);
    if (t >= lengths[b]) return;
    const float4* e4 = (const float4*)(enc + (size_t)wid * DD);
    const float4 x0 = e4[lane * 2];
    const float4 x1 = e4[lane * 2 + 1];
    float acc[3];
    #pragma unroll
    for (int i = 0; i < 3; i++) {
        const float4* q4 = (const float4*)(q + (size_t)(i * BB + b) * DD);
        const float4 y0 = q4[lane * 2];
        const float4 y1 = q4[lane * 2 + 1];
        acc[i] = x0.x * y0.x + x0.y * y0.y + x0.z * y0.z + x0.w * y0.w
               + x1.x * y1.x + x1.y * y1.y + x1.z * y1.z + x1.w * y1.w;
    }
    #pragma unroll
    for (int m = 32; m >= 1; m >>= 1) {
        acc[0] += __shfl_xor(acc[0], m, 64);
        acc[1] += __shfl_xor(acc[1], m, 64);
        acc[2] += __shfl_xor(acc[2], m, 64);
    }
    if (lane == 0) {
        p[(size_t)(0 * BB + b) * TT + t] = acc[0];
        p[(size_t)(1 * BB + b) * TT + t] = acc[1];
        p[(size_t)(2 * BB + b) * TT + t] = acc[2];
    }
}

// ------- K4: windowed softmax per (i,b); emit pool weights w and att ---------
__global__ void __launch_bounds__(1024) k_softmax(const float* __restrict__ p,
                                                  const int* __restrict__ lengths,
                                                  float* __restrict__ w,
                                                  float* __restrict__ att_out) {
    __shared__ float sred[16];
    __shared__ float sbc;
    const int ib = blockIdx.x;            // 48 blocks
    const int b = ib % BB;
    const int i = ib / BB;
    const int k = i + 1;
    const float invk = 1.0f / (float)k;
    int V = lengths[b] - k + 1;           // count of valid window positions
    if (V < 0) V = 0;
    const float* pp = p + (size_t)ib * TT;
    const int tid = threadIdx.x;

    // phase 1: max over valid windowed scores
    float local = -3.4e38f;
    for (int l = tid; l < V; l += 1024) {
        float s = pp[l];
        if (k > 1) s += pp[l + 1];
        if (k > 2) s += pp[l + 2];
        local = fmaxf(local, s * invk);
    }
    float v = local;
    #pragma unroll
    for (int m = 32; m >= 1; m >>= 1) v = fmaxf(v, __shfl_xor(v, m, 64));
    if ((tid & 63) == 0) sred[tid >> 6] = v;
    __syncthreads();
    if (tid < 16) {
        float x = sred[tid];
        #pragma unroll
        for (int m = 8; m >= 1; m >>= 1) x = fmaxf(x, __shfl_xor(x, m, 16));
        if (tid == 0) sbc = x;
    }
    __syncthreads();
    const float mmax = sbc;
    __syncthreads();

    // phase 2: sum of exps
    float lsum = 0.f;
    for (int l = tid; l < V; l += 1024) {
        float s = pp[l];
        if (k > 1) s += pp[l + 1];
        if (k > 2) s += pp[l + 2];
        lsum += __expf(s * invk - mmax);
    }
    v = lsum;
    #pragma unroll
    for (int m = 32; m >= 1; m >>= 1) v += __shfl_xor(v, m, 64);
    if ((tid & 63) == 0) sred[tid >> 6] = v;
    __syncthreads();
    if (tid < 16) {
        float x = sred[tid];
        #pragma unroll
        for (int m = 8; m >= 1; m >>= 1) x += __shfl_xor(x, m, 16);
        if (tid == 0) sbc = x;
    }
    __syncthreads();
    const float inv = 1.0f / sbc;

    // phase 3: pool weights w_i[b,t] = (1/k) * sum_{j<k} a_i[b,t-j]
    for (int t = tid; t < TT; t += 1024) {
        float acc = 0.f;
        #pragma unroll
        for (int j = 0; j < 3; j++) {
            if (j < k) {
                const int l = t - j;
                if (l >= 0 && l < V) {
                    float s = pp[l];
                    if (k > 1) s += pp[l + 1];
                    if (k > 2) s += pp[l + 2];
                    acc += __expf(s * invk - mmax);
                }
            }
        }
        acc *= inv * invk;
        w[(size_t)ib * TT + t] = acc;
        if (i == 0) att_out[(size_t)b * TT + t] = acc;  // k=1: w == att
    }
}

// ------- K5a: per-chunk partials part[i][y][b][:] = sum_{t in chunk} w*enc ---
// No atomics: each (b, y) block owns its partial slice. w[t]==0 for t>=len_b,
// so rows past len_b are skipped entirely.
__global__ void __launch_bounds__(128) k_pool(const float* __restrict__ enc,
                                              const float* __restrict__ w,
                                              const int* __restrict__ lengths,
                                              float* __restrict__ part) {
    const int b = blockIdx.x;
    const int y = blockIdx.y;
    const int t0 = y * (TT / NCHUNK);
    const int d4 = threadIdx.x;           // float4 column, 0..127
    int tend = t0 + (TT / NCHUNK);
    const int len = lengths[b];
    if (tend > len) tend = len;
    float4 a0 = {0, 0, 0, 0}, a1 = {0, 0, 0, 0}, a2 = {0, 0, 0, 0};
    const float* wb0 = w + (size_t)(0 * BB + b) * TT;
    const float* wb1 = w + (size_t)(1 * BB + b) * TT;
    const float* wb2 = w + (size_t)(2 * BB + b) * TT;
    for (int t = t0; t < tend; ++t) {
        const float4 x = ((const float4*)(enc + ((size_t)b * TT + t) * DD))[d4];
        const float w0 = wb0[t], w1 = wb1[t], w2 = wb2[t];
        a0.x += w0 * x.x; a0.y += w0 * x.y; a0.z += w0 * x.z; a0.w += w0 * x.w;
        a1.x += w1 * x.x; a1.y += w1 * x.y; a1.z += w1 * x.z; a1.w += w1 * x.w;
        a2.x += w2 * x.x; a2.y += w2 * x.y; a2.z += w2 * x.z; a2.w += w2 * x.w;
    }
    ((float4*)(part + ((size_t)((0 * NCHUNK + y) * BB) + b) * DD))[d4] = a0;
    ((float4*)(part + ((size_t)((1 * NCHUNK + y) * BB) + b) * DD))[d4] = a1;
    ((float4*)(part + ((size_t)((2 * NCHUNK + y) * BB) + b) * DD))[d4] = a2;
}

// ------- K5b: pooled[i][b][d] = sum_y part[i][y][b][d] -----------------------
__global__ void __launch_bounds__(256) k_pool_reduce(const float* __restrict__ part,
                                                     float* __restrict__ pooled) {
    const int idx = blockIdx.x * 256 + threadIdx.x;   // (i*BB+b)*DD + d
    const int i = idx / (BB * DD);
    const int bd = idx % (BB * DD);
    float s = 0.f;
    const float* base = part + (size_t)i * NCHUNK * BB * DD + bd;
    #pragma unroll 8
    for (int y = 0; y < NCHUNK; y++) s += base[(size_t)y * BB * DD];
    pooled[idx] = s;
}

// -------- K6: ctx[b,e] = sum_i (pooled_i[b,:] . Ww[i,e,:]) + sum_i Wb[i,e] ---
__global__ void __launch_bounds__(256) k_ctx(const float* __restrict__ pooled,
                                             const float* __restrict__ Ww,
                                             const float* __restrict__ Wb,
                                             float* __restrict__ ctx) {
    const int wid = blockIdx.x * 4 + (threadIdx.x >> 6);   // b*512 + e
    const int lane = threadIdx.x & 63;
    const int b = wid >> 9;
    const int e = wid & 511;
    float acc = 0.f;
    #pragma unroll
    for (int i = 0; i < 3; i++) {
        const float4* pr = (const float4*)(pooled + (size_t)(i * BB + b) * DD);
        const float4* wr = (const float4*)(Ww + ((size_t)i * DD + e) * DD);
        const float4 p0 = pr[lane * 2], p1 = pr[lane * 2 + 1];
        const float4 w0 = wr[lane * 2], w1 = wr[lane * 2 + 1];
        acc += p0.x * w0.x + p0.y * w0.y + p0.z * w0.z + p0.w * w0.w
             + p1.x * w1.x + p1.y * w1.y + p1.z * w1.z + p1.w * w1.w;
    }
    #pragma unroll
    for (int m = 32; m >= 1; m >>= 1) acc += __shfl_xor(acc, m, 64);
    if (lane == 0)
        ctx[(size_t)b * DD + e] = acc + Wb[e] + Wb[DD + e] + Wb[2 * DD + e];
}

extern "C" void kernel_launch(void* const* d_in, const int* in_sizes, int n_in,
                              void* d_out, int out_size, void* d_ws, size_t ws_size,
                              hipStream_t stream) {
    const float* s_prev = (const float*)d_in[0];
    const float* enc    = (const float*)d_in[1];
    const void*  mask   = d_in[2];
    const float* Vw     = (const float*)d_in[3];
    // d_in[4] = Vb: dead — constant shift under softmax
    const float* Ww     = (const float*)d_in[5];
    const float* Wb     = (const float*)d_in[6];

    float* out = (float*)d_out;
    float* ctx = out;              // [B, D]
    float* att = out + BB * DD;    // [B, T]

    float* W       = (float*)d_ws;
    int*   lengths = (int*)d_ws;                 // 16 ints in first 64 floats
    float* q       = W + OFF_Q;
    float* p       = W + OFF_P;
    float* wbuf    = W + OFF_W;
    float* pooled  = W + OFF_POOL;
    float* part    = W + OFF_PART;

    k_lengths<<<1, 1024, 0, stream>>>((const unsigned char*)mask, lengths);
    k_q<<<3 * BB, 256, 0, stream>>>(s_prev, Vw, q);
    k_scores<<<BB * TT / 4, 256, 0, stream>>>(enc, q, lengths, p);
    k_softmax<<<3 * BB, 1024, 0, stream>>>(p, lengths, wbuf, att);
    k_pool<<<dim3(BB, NCHUNK), 128, 0, stream>>>(enc, wbuf, lengths, part);
    k_pool_reduce<<<3 * BB * DD / 256, 256, 0, stream>>>(part, pooled);
    k_ctx<<<BB * DD / 4, 256, 0, stream>>>(pooled, Ww, Wb, ctx);
}

// Round 3
// 266.617 us; speedup vs baseline: 1.2402x; 1.0441x over previous
//
#include <hip/hip_runtime.h>

#define BB 16
#define TT 4096
#define DD 512
#define CH 16               // rows per chunk in fused kernel
#define NY (TT/CH)          // 256 chunks per batch row
#define NEG (-1.0e30f)

// workspace float offsets
#define OFF_Q     64                         // 3*BB*DD
#define OFF_QP    (OFF_Q + 3*BB*DD)          // 4*3*BB*DD  (e-split partials)
#define OFF_P0    (OFF_QP + 4*3*BB*DD)       // BB*TT      (level-0 dots for att)
#define OFF_M     (OFF_P0 + BB*TT)           // 3*BB*NY    (per-chunk local max)
#define OFF_S     (OFF_M + 3*BB*NY)          // 3*BB*NY    (per-chunk exp-sum)
#define OFF_SC    (OFF_S + 3*BB*NY)          // 3*BB*NY    (per-chunk scale)
#define OFF_MT    (OFF_SC + 3*BB*NY)         // 64         (per-(i,b) global max)
#define OFF_TOT   (OFF_MT + 64)              // 64         (per-(i,b) total)
#define OFF_PART  (OFF_TOT + 64)             // 3*NY*BB*DD (pooled partials, 25MB)
#define OFF_POOL  (OFF_PART + 3*NY*BB*DD)    // 3*BB*DD

// ---------------- K1: mask layout detection + per-batch lengths --------------
__global__ void __launch_bounds__(1024) k_lengths(const unsigned char* mask, int* lengths) {
    __shared__ int sflag;
    const int tid = threadIdx.x;
    if (tid == 0) sflag = 0;
    __syncthreads();
    int f = 0;
    for (int idx = tid * 4 + 1; idx < BB * TT; idx += 1024 * 4)
        f |= (mask[idx] != 0);
    if (f) atomicOr(&sflag, 1);
    __syncthreads();
    const bool byte_layout = (sflag != 0);
    const int* m32 = (const int*)mask;
    const int b = tid >> 6;
    const int lane = tid & 63;
    int cnt = 0;
    if (byte_layout) {
        for (int t = lane; t < TT; t += 64) cnt += (mask[b * TT + t] != 0);
    } else {
        for (int t = lane; t < TT; t += 64) cnt += (m32[b * TT + t] != 0);
    }
    #pragma unroll
    for (int m = 32; m >= 1; m >>= 1) cnt += __shfl_xor(cnt, m, 64);
    if (lane == 0) lengths[b] = TT - cnt;
}

// ------- K2: qpart[(i,b,ec),d] = sum_{e in ec-range} s_prev[b,e]*Vw[i,e,d] ---
__global__ void __launch_bounds__(256) k_q(const float* __restrict__ s_prev,
                                           const float* __restrict__ Vw,
                                           float* __restrict__ qpart) {
    const int blk = blockIdx.x;           // ((i*BB+b)*4 + ec), 192 blocks
    const int ec = blk & 3;
    const int ib = blk >> 2;
    const int b = ib % BB;
    const int i = ib / BB;
    const int d0 = threadIdx.x;
    const float* sp = s_prev + b * DD + ec * 128;
    const float* W = Vw + (size_t)i * DD * DD + (size_t)(ec * 128) * DD;
    float a0 = 0.f, a1 = 0.f;
    for (int e = 0; e < 128; e++) {
        const float se = sp[e];
        a0 += se * W[e * DD + d0];
        a1 += se * W[e * DD + d0 + 256];
    }
    qpart[(size_t)blk * DD + d0] = a0;
    qpart[(size_t)blk * DD + d0 + 256] = a1;
}

__global__ void __launch_bounds__(256) k_q_reduce(const float* __restrict__ qpart,
                                                  float* __restrict__ q) {
    const int idx = blockIdx.x * 256 + threadIdx.x;  // ib*DD+d, 24576
    const int ib = idx / DD;
    const int d = idx % DD;
    float s = 0.f;
    #pragma unroll
    for (int ec = 0; ec < 4; ec++) s += qpart[(size_t)(ib * 4 + ec) * DD + d];
    q[idx] = s;
}

// ---- K3 fused: dots + local windowed softmax + weighted pooling, 1 enc pass -
// Block = (b, chunk y): rows [t0, t0+CH) plus 2 boundary rows.
__global__ void __launch_bounds__(256) k_fused(const float* __restrict__ enc,
                                               const float* __restrict__ q,
                                               const int* __restrict__ lengths,
                                               float* __restrict__ p0,
                                               float* __restrict__ mbuf,
                                               float* __restrict__ sbuf,
                                               float* __restrict__ part) {
    __shared__ float sp[CH + 2][3];   // per-row dots, 3 levels
    __shared__ float svs[3][CH];      // windowed scores
    __shared__ float su[3][CH];       // raw exp weights
    __shared__ float sm[3];           // local max
    const int b = blockIdx.x;
    const int y = blockIdx.y;
    const int t0 = y * CH;
    const int len = lengths[b];
    const int tid = threadIdx.x;
    if (t0 >= len) {                  // fully masked chunk (block-uniform)
        if (tid < 3) {
            mbuf[(size_t)(tid * BB + b) * NY + y] = NEG;
            sbuf[(size_t)(tid * BB + b) * NY + y] = 0.f;
        }
        return;
    }
    const int wv = tid >> 6, lane = tid & 63;

    // --- phase A: dots p_i[t] = enc[t] . q_i[b] for rows t0..t0+17 ---
    const float4* q40 = (const float4*)(q + (size_t)(0 * BB + b) * DD);
    const float4* q41 = (const float4*)(q + (size_t)(1 * BB + b) * DD);
    const float4* q42 = (const float4*)(q + (size_t)(2 * BB + b) * DD);
    const float4 qa0 = q40[lane], qb0 = q40[64 + lane];
    const float4 qa1 = q41[lane], qb1 = q41[64 + lane];
    const float4 qa2 = q42[lane], qb2 = q42[64 + lane];
    #pragma unroll
    for (int rr = 0; rr < 5; rr++) {
        if (rr == 4 && wv >= 2) break;                 // extras: wave0->r16, wave1->r17
        const int r = (rr < 4) ? (wv + rr * 4) : (CH + wv);
        const int t = t0 + r;
        float d0 = 0.f, d1 = 0.f, d2 = 0.f;
        if (t < len) {                                  // wave-uniform
            const float4* e4 = (const float4*)(enc + ((size_t)b * TT + t) * DD);
            const float4 x0 = e4[lane], x1 = e4[64 + lane];
            d0 = x0.x*qa0.x + x0.y*qa0.y + x0.z*qa0.z + x0.w*qa0.w
               + x1.x*qb0.x + x1.y*qb0.y + x1.z*qb0.z + x1.w*qb0.w;
            d1 = x0.x*qa1.x + x0.y*qa1.y + x0.z*qa1.z + x0.w*qa1.w
               + x1.x*qb1.x + x1.y*qb1.y + x1.z*qb1.z + x1.w*qb1.w;
            d2 = x0.x*qa2.x + x0.y*qa2.y + x0.z*qa2.z + x0.w*qa2.w
               + x1.x*qb2.x + x1.y*qb2.y + x1.z*qb2.z + x1.w*qb2.w;
            #pragma unroll
            for (int m = 32; m >= 1; m >>= 1) {
                d0 += __shfl_xor(d0, m, 64);
                d1 += __shfl_xor(d1, m, 64);
                d2 += __shfl_xor(d2, m, 64);
            }
        }
        if (lane == 0) {
            sp[r][0] = d0; sp[r][1] = d1; sp[r][2] = d2;
            if (rr < 4 && t < len) p0[(size_t)b * TT + t] = d0;
        }
    }
    __syncthreads();

    // --- windowed scores ---
    if (tid < 48) {
        const int i = tid / CH, r = tid % CH;
        const int l = t0 + r;
        const bool valid = l < (len - i);              // l <= len-k
        float s = sp[r][i];
        if (i > 0) s += sp[r + 1][i];
        if (i > 1) s += sp[r + 2][i];
        svs[i][r] = valid ? s * (1.0f / (float)(i + 1)) : NEG;
    }
    __syncthreads();
    if (tid < 3) {
        float m = NEG;
        #pragma unroll
        for (int r = 0; r < CH; r++) m = fmaxf(m, svs[tid][r]);
        sm[tid] = m;
    }
    __syncthreads();
    if (tid < 48) {
        const int i = tid / CH, r = tid % CH;
        const bool valid = (t0 + r) < (len - i);
        su[i][r] = valid ? __expf(svs[i][r] - sm[i]) : 0.f;
    }
    __syncthreads();
    if (tid < 3) {
        float s = 0.f;
        #pragma unroll
        for (int r = 0; r < CH; r++) s += su[tid][r];
        mbuf[(size_t)(tid * BB + b) * NY + y] = sm[tid];
        sbuf[(size_t)(tid * BB + b) * NY + y] = s;
    }
    __syncthreads();

    // --- phase B: partial pooled = sum_l u_l * ngram_l (rolling 3-row window) -
    const int d = tid * 2;    // two float columns per thread
    const float* col = enc + (size_t)b * TT * DD + d;
    float2 va, vb2, vc;
    {
        const int t = t0;
        va  = (t     < TT) ? *(const float2*)(col + (size_t)t * DD)       : make_float2(0.f, 0.f);
        vb2 = (t + 1 < TT) ? *(const float2*)(col + (size_t)(t + 1) * DD) : make_float2(0.f, 0.f);
    }
    float2 a0 = {0, 0}, a1 = {0, 0}, a2 = {0, 0};
    #pragma unroll
    for (int r = 0; r < CH; r++) {
        const int t = t0 + r;
        vc = (t + 2 < TT) ? *(const float2*)(col + (size_t)(t + 2) * DD) : make_float2(0.f, 0.f);
        const float u0 = su[0][r], u1 = su[1][r], u2 = su[2][r];
        const float w1x = va.x + vb2.x, w1y = va.y + vb2.y;
        const float w2x = w1x + vc.x,   w2y = w1y + vc.y;
        a0.x += u0 * va.x;  a0.y += u0 * va.y;
        a1.x += u1 * w1x;   a1.y += u1 * w1y;
        a2.x += u2 * w2x;   a2.y += u2 * w2y;
        va = vb2; vb2 = vc;
    }
    a1.x *= 0.5f; a1.y *= 0.5f;
    a2.x *= (1.0f / 3.0f); a2.y *= (1.0f / 3.0f);
    float* pt = part + (size_t)y * BB * DD + (size_t)b * DD + d;
    *(float2*)(pt)                        = a0;
    *(float2*)(pt + (size_t)NY * BB * DD)     = a1;
    *(float2*)(pt + (size_t)2 * NY * BB * DD) = a2;
}

// ------- K4: per-(i,b) global max/total + per-chunk scales -------------------
__global__ void __launch_bounds__(256) k_combine(const float* __restrict__ mbuf,
                                                 const float* __restrict__ sbuf,
                                                 float* __restrict__ scale,
                                                 float* __restrict__ mtot,
                                                 float* __restrict__ tot) {
    const int g = blockIdx.x * 4 + (threadIdx.x >> 6);  // (i*BB+b), 48 waves
    const int lane = threadIdx.x & 63;
    const float* mv = mbuf + (size_t)g * NY;
    const float* sv = sbuf + (size_t)g * NY;
    float ml[4], sl[4];
    float m = NEG;
    #pragma unroll
    for (int j = 0; j < 4; j++) {
        ml[j] = mv[lane * 4 + j];
        sl[j] = sv[lane * 4 + j];
        m = fmaxf(m, ml[j]);
    }
    #pragma unroll
    for (int s = 32; s >= 1; s >>= 1) m = fmaxf(m, __shfl_xor(m, s, 64));
    float t = 0.f;
    #pragma unroll
    for (int j = 0; j < 4; j++) t += sl[j] * __expf(ml[j] - m);
    #pragma unroll
    for (int s = 32; s >= 1; s >>= 1) t += __shfl_xor(t, s, 64);
    const float inv = 1.0f / t;
    #pragma unroll
    for (int j = 0; j < 4; j++)
        scale[(size_t)g * NY + lane * 4 + j] = __expf(ml[j] - m) * inv;
    if (lane == 0) { mtot[g] = m; tot[g] = t; }
}

// ------- K5: pooled[(i,b),d] = sum_y part[i][y][b][d] * scale[(i,b),y] -------
__global__ void __launch_bounds__(256) k_reduce(const float* __restrict__ part,
                                                const float* __restrict__ scale,
                                                float* __restrict__ pooled) {
    const int idx = blockIdx.x * 256 + threadIdx.x;  // (i*BB+b)*DD + d
    const int ib = idx / DD;
    const int d = idx % DD;
    const int i = ib / BB, b = ib % BB;
    const float* sc = scale + (size_t)ib * NY;
    const float* base = part + (size_t)i * NY * BB * DD + (size_t)b * DD + d;
    float s = 0.f;
    #pragma unroll 8
    for (int y = 0; y < NY; y++) s += base[(size_t)y * BB * DD] * sc[y];
    pooled[idx] = s;
}

// ------- K6: att[b,t] = (t<len) ? exp(p0-m)/total : 0  (level 0) -------------
__global__ void __launch_bounds__(256) k_att(const float* __restrict__ p0,
                                             const int* __restrict__ lengths,
                                             const float* __restrict__ mtot,
                                             const float* __restrict__ tot,
                                             float* __restrict__ att) {
    const int idx = blockIdx.x * 256 + threadIdx.x;  // b*TT + t
    const int b = idx >> 12;
    const int t = idx & (TT - 1);
    const float m = mtot[b];
    const float inv = 1.0f / tot[b];
    att[idx] = (t < lengths[b]) ? __expf(p0[idx] - m) * inv : 0.f;
}

// -------- K7: ctx[b,e] = sum_i (pooled_i[b,:] . Ww[i,e,:]) + sum_i Wb[i,e] ---
__global__ void __launch_bounds__(256) k_ctx(const float* __restrict__ pooled,
                                             const float* __restrict__ Ww,
                                             const float* __restrict__ Wb,
                                             float* __restrict__ ctx) {
    const int wid = blockIdx.x * 4 + (threadIdx.x >> 6);   // b*512 + e
    const int lane = threadIdx.x & 63;
    const int b = wid >> 9;
    const int e = wid & 511;
    float acc = 0.f;
    #pragma unroll
    for (int i = 0; i < 3; i++) {
        const float4* pr = (const float4*)(pooled + (size_t)(i * BB + b) * DD);
        const float4* wr = (const float4*)(Ww + ((size_t)i * DD + e) * DD);
        const float4 p0 = pr[lane], p1 = pr[64 + lane];
        const float4 w0 = wr[lane], w1 = wr[64 + lane];
        acc += p0.x * w0.x + p0.y * w0.y + p0.z * w0.z + p0.w * w0.w
             + p1.x * w1.x + p1.y * w1.y + p1.z * w1.z + p1.w * w1.w;
    }
    #pragma unroll
    for (int m = 32; m >= 1; m >>= 1) acc += __shfl_xor(acc, m, 64);
    if (lane == 0)
        ctx[(size_t)b * DD + e] = acc + Wb[e] + Wb[DD + e] + Wb[2 * DD + e];
}

extern "C" void kernel_launch(void* const* d_in, const int* in_sizes, int n_in,
                              void* d_out, int out_size, void* d_ws, size_t ws_size,
                              hipStream_t stream) {
    const float* s_prev = (const float*)d_in[0];
    const float* enc    = (const float*)d_in[1];
    const void*  mask   = d_in[2];
    const float* Vw     = (const float*)d_in[3];
    // d_in[4] = Vb: dead — constant shift under softmax
    const float* Ww     = (const float*)d_in[5];
    const float* Wb     = (const float*)d_in[6];

    float* out = (float*)d_out;
    float* ctx = out;              // [B, D]
    float* att = out + BB * DD;    // [B, T]

    float* W       = (float*)d_ws;
    int*   lengths = (int*)d_ws;
    float* q       = W + OFF_Q;
    float* qpart   = W + OFF_QP;
    float* p0      = W + OFF_P0;
    float* mbuf    = W + OFF_M;
    float* sbuf    = W + OFF_S;
    float* scale   = W + OFF_SC;
    float* mtot    = W + OFF_MT;
    float* tot     = W + OFF_TOT;
    float* part    = W + OFF_PART;
    float* pooled  = W + OFF_POOL;

    k_lengths<<<1, 1024, 0, stream>>>((const unsigned char*)mask, lengths);
    k_q<<<192, 256, 0, stream>>>(s_prev, Vw, qpart);
    k_q_reduce<<<3 * BB * DD / 256, 256, 0, stream>>>(qpart, q);
    k_fused<<<dim3(BB, NY), 256, 0, stream>>>(enc, q, lengths, p0, mbuf, sbuf, part);
    k_combine<<<12, 256, 0, stream>>>(mbuf, sbuf, scale, mtot, tot);
    k_reduce<<<3 * BB * DD / 256, 256, 0, stream>>>(part, scale, pooled);
    k_att<<<BB * TT / 256, 256, 0, stream>>>(p0, lengths, mtot, tot, att);
    k_ctx<<<BB * DD / 4, 256, 0, stream>>>(pooled, Ww, Wb, ctx);
}